// Round 5
// baseline (161.330 us; speedup 1.0000x reference)
//
#include <hip/hip_runtime.h>
#include <cmath>

#define KCLS 10
#define NCELL 3721          // 61*61
#define BIGV  0x0FFFFFFF

// d_out layout (all float32), concatenated in reference return order
#define OUT_PROB 0
#define OUT_LAB  37210
#define OUT_BOX  74420
#define OUT_VALID 223300

// padded pixel-row: raw float index p stored at p + 4*(p/48).
// Lane c reads b128 @ dword 13*(c+tq) + u: 13 odd -> lanes c and c+32 alias
// (2-way = free), all other lanes distinct bank-quads -> minimal-conflict.
#define XROW_PAD 3328       // 3072 + 4*64

// helper: element n (compile-time after unroll) of a float4[5] block
#define WF(q, n) ( ((n)&3)==0 ? (q)[(n)>>2].x : ((n)&3)==1 ? (q)[(n)>>2].y : \
                   ((n)&3)==2 ? (q)[(n)>>2].z : (q)[(n)>>2].w )

// ---------------- Stage 1a: partial logits ---------------------------------
// Grid 1984 = 64 i-rows x 31 r-pairs; 256 threads = 4 waves (t-quarters),
// lane = patch column c. LDS ~39 KB -> 4 blocks/CU = 16 waves/CU.
// Per u-step per wave: 2 per-lane ds_read_b128 (x rows A,B) + 10 uniform
// ds_read_b128 (W broadcast) + 80 v_fma, with W reads ping-pong prefetched
// in two 5-read halves (wq[2][5]) so LDS latency overlaps FMA issue.
__global__ __launch_bounds__(256, 4) void k1a_partial(
    const float* __restrict__ x, const float* __restrict__ W,
    float* __restrict__ partial)
{
    const int tid  = threadIdx.x;
    const int bid  = blockIdx.x;          // 0..1983
    const int ip   = bid / 31;            // 0..63  pixel-row-in-patch
    const int g    = bid - ip * 31;       // 0..30  r-pair
    const int ra   = g * 2;               // even patch row
    const int lane = tid & 63;
    const int tq   = tid >> 6;            // t-quarter 0..3
    const int cc   = (lane < 61) ? lane : 60;   // dup lanes, add/write-guarded

    __shared__ float xrowA[XROW_PAD];     // 13.3 KiB
    __shared__ float xrowB[XROW_PAD];     // 13.3 KiB
    __shared__ float wlds[192 * KCLS];    // 7.7 KiB  (W rows d = ip*192..+191)
    __shared__ float red[2][61][KCLS];    // 4.9 KiB

    // zero red (covered by the staging barrier)
    for (int s = tid; s < 2 * 61 * KCLS; s += 256) ((float*)red)[s] = 0.0f;

    // stage W window (480 float4s, coalesced)
    {
        const float* wsrc = W + (size_t)ip * 1920;
#pragma unroll
        for (int j = 0; j < 2; ++j) {
            const int idx = tid + (j << 8);
            if (idx < 480)
                *(float4*)(wlds + (idx << 2)) = *(const float4*)(wsrc + (idx << 2));
        }
    }
    // stage 2 pixel rows (patch rows ra, ra+1), padded
    {
        const int prA = (ra * 16) + ip;                  // <= 60*16+63 = 1023
        int prB = (ra + 1) * 16 + ip;
        if (prB > 1023) prB = 1023;                      // g=30 dup, write-guarded
        const float* gA = x + (size_t)prA * 3072;
        const float* gB = x + (size_t)prB * 3072;
#pragma unroll
        for (int j = 0; j < 3; ++j) {
            const int idx = tid + (j << 8);              // 0..767 float4s
            const int p   = idx << 2;                    // p%48<=44: same pad group
            const int dst = p + ((p / 48) << 2);
            const float4 va = *(const float4*)(gA + p);
            xrowA[dst] = va.x; xrowA[dst+1] = va.y; xrowA[dst+2] = va.z; xrowA[dst+3] = va.w;
            const float4 vb = *(const float4*)(gB + p);
            xrowB[dst] = vb.x; xrowB[dst+1] = vb.y; xrowB[dst+2] = vb.z; xrowB[dst+3] = vb.w;
        }
    }
    __syncthreads();

    float accA[KCLS], accB[KCLS];
#pragma unroll
    for (int k = 0; k < KCLS; ++k) { accA[k] = 0.0f; accB[k] = 0.0f; }

    const float* wb = wlds + tq * 480;           // this wave's 48-d window
    const float* lA = &xrowA[52 * (cc + tq)];
    const float* lB = &xrowB[52 * (cc + tq)];

    float4 wq0[5], wq1[5];
#pragma unroll
    for (int q = 0; q < 5; ++q) wq0[q] = *(const float4*)(wb + (q << 2));

#pragma unroll 2
    for (int u = 0; u < 12; ++u) {
        const float4 xa = *(const float4*)(lA + (u << 2));
        const float4 xb = *(const float4*)(lB + (u << 2));
        const float* wu = wb + 40 * u;

        // prefetch half1 (e=2,3) before computing half0
#pragma unroll
        for (int q = 0; q < 5; ++q) wq1[q] = *(const float4*)(wu + 20 + (q << 2));

        // half0: e=0 (k0..9), e=1 (k0..9)
#pragma unroll
        for (int k = 0; k < KCLS; ++k) {
            accA[k] += xa.x * WF(wq0, k);       accB[k] += xb.x * WF(wq0, k);
            accA[k] += xa.y * WF(wq0, 10 + k);  accB[k] += xb.y * WF(wq0, 10 + k);
        }

        // prefetch half0 of next u before computing half1
        if (u + 1 < 12) {
#pragma unroll
            for (int q = 0; q < 5; ++q) wq0[q] = *(const float4*)(wu + 40 + (q << 2));
        }

        // half1: e=2, e=3
#pragma unroll
        for (int k = 0; k < KCLS; ++k) {
            accA[k] += xa.z * WF(wq1, k);       accB[k] += xb.z * WF(wq1, k);
            accA[k] += xa.w * WF(wq1, 10 + k);  accB[k] += xb.w * WF(wq1, 10 + k);
        }
    }

    // cross-wave reduce (ds_add_f32); order nondeterminism ~1e-7 vs 1e-3 margins
    if (lane < 61) {
#pragma unroll
        for (int k = 0; k < KCLS; ++k) {
            atomicAdd(&red[0][cc][k], accA[k]);
            atomicAdd(&red[1][cc][k], accB[k]);
        }
    }
    __syncthreads();

    // write partials: slot ip, rows ra and ra+1 (layout [ip][r][c][k])
    for (int t = tid; t < 610; t += 256)
        partial[(size_t)ip * 37210 + (size_t)ra * 610 + t] = ((const float*)red)[t];
    if (ra + 1 <= 60) {
        for (int t = tid; t < 610; t += 256)
            partial[(size_t)ip * 37210 + (size_t)(ra + 1) * 610 + t]
                = ((const float*)red)[610 + t];
    }
}

// ---------------- Stage 1b: reduce partials + bias + softmax ---------------
__global__ __launch_bounds__(640) void k1b_softmax(
    const float* __restrict__ partial, const float* __restrict__ b,
    float* __restrict__ out)
{
    const int r   = blockIdx.x;           // 0..60
    const int tid = threadIdx.x;
    __shared__ double lgs[61][KCLS];

    if (tid < 610) {
        const int c = tid / 10, k = tid - c * 10;
        double s = (double)b[k];
        const float* p = partial + (size_t)r * 610 + tid;
#pragma unroll 8
        for (int ip = 0; ip < 64; ++ip)
            s += (double)p[(size_t)ip * 37210];
        lgs[c][k] = s;
    }
    __syncthreads();

    if (tid < 61) {
        double l[KCLS];
#pragma unroll
        for (int k = 0; k < KCLS; ++k) l[k] = lgs[tid][k];
        double m = l[0];
#pragma unroll
        for (int k = 1; k < KCLS; ++k) m = fmax(m, l[k]);
        double e[KCLS], ssum = 0.0;
#pragma unroll
        for (int k = 0; k < KCLS; ++k) { e[k] = exp(l[k] - m); ssum += e[k]; }
        const double inv = 1.0 / ssum;
        float* po = out + OUT_PROB + (size_t)(r * 61 + tid) * KCLS;
#pragma unroll
        for (int k = 0; k < KCLS; ++k) po[k] = (float)(e[k] * inv);
    }
}

// ---------------- Stage 2+3 fused: CC (union-find hooking) + boxes ---------
// One block per class. Labels stored as LDS OFFSETS (off = (r+1)*64 + c+1):
// min-off == min-idx (both lexicographic in (r,c)). Root chase + atomicMin
// hooking = path compression -> ~3-6 rounds instead of O(diameter).
__global__ __launch_bounds__(1024) void k2_cc_boxes(float* __restrict__ out)
{
    const int k   = blockIdx.x;
    const int tid = threadIdx.x;

    __shared__ int lab[63 * 64];
    __shared__ int act[NCELL];
    __shared__ int nact, changed;
    __shared__ int rmn[NCELL + 1], rmx[NCELL + 1], cmn[NCELL + 1], cmx[NCELL + 1];

    for (int idx = tid; idx < 63 * 64; idx += 1024) lab[idx] = BIGV;
    for (int s = tid; s <= NCELL; s += 1024) {
        rmn[s] = 0x7fffffff; cmn[s] = 0x7fffffff; rmx[s] = -1; cmx[s] = -1;
    }
    if (tid == 0) nact = 0;
    __syncthreads();

    for (int idx = tid; idx < NCELL; idx += 1024) {
        const float pv = out[OUT_PROB + (size_t)idx * KCLS + k];
        if (pv > 0.7f) {
            const int r = idx / 61, c = idx - r * 61;
            const int off = (r + 1) * 64 + (c + 1);
            lab[off] = off;
            act[atomicAdd(&nact, 1)] = off;
        }
    }
    __syncthreads();
    const int na = nact;

    for (int round = 0; round < 128; ++round) {
        if (tid == 0) changed = 0;
        __syncthreads();
        bool ch = false;
        for (int ii = tid; ii < na; ii += 1024) {
            const int off = act[ii];
            const int v = lab[off];
            int m = v, t;
            t = lab[off - 1];  if (t < m) m = t;
            t = lab[off + 1];  if (t < m) m = t;
            t = lab[off - 64]; if (t < m) m = t;
            t = lab[off + 64]; if (t < m) m = t;
            if (m < v) {
                int p = lab[m];                       // chase to current root
                while (p < m) { m = p; p = lab[m]; }  // strictly decreasing
                atomicMin(&lab[off], m);              // compress self
                atomicMin(&lab[v],   m);              // hook old root (union)
                ch = true;
            }
        }
        if (ch) changed = 1;       // benign race
        __syncthreads();
        if (changed == 0) break;   // no writes between the barriers -> uniform
        __syncthreads();           // protect next round's reset
    }

    // write labels (convert off -> idx+1)
    for (int idx = tid; idx < NCELL; idx += 1024) {
        const int r = idx / 61, c = idx - r * 61;
        const int v = lab[(r + 1) * 64 + (c + 1)];
        const int lv = (v < BIGV) ? ((v >> 6) * 61 - 61 + (v & 63)) : 0;
        out[OUT_LAB + (size_t)idx * KCLS + k] = (float)lv;
    }

    // boxes: segment min/max over active cells only
    for (int ii = tid; ii < na; ii += 1024) {
        const int off = act[ii];
        const int v = lab[off];
        const int lb = (v >> 6) * 61 - 61 + (v & 63);
        const int r = (off >> 6) - 1, c = (off & 63) - 1;
        atomicMin(&rmn[lb], r); atomicMax(&rmx[lb], r);
        atomicMin(&cmn[lb], c); atomicMax(&cmx[lb], c);
    }
    __syncthreads();

    for (int s = tid; s <= NCELL; s += 1024) {
        const bool val = (s > 0) && (rmx[s] >= 0);
        float* bo = out + OUT_BOX + (size_t)(k * (NCELL + 1) + s) * 4;
        if (val) {
            bo[0] = (float)(rmn[s] - 1);
            bo[1] = (float)(cmn[s] - 1);
            bo[2] = (float)(rmx[s] + 1);
            bo[3] = (float)(cmx[s] + 1);
        } else {
            bo[0] = 0.0f; bo[1] = 0.0f; bo[2] = 0.0f; bo[3] = 0.0f;
        }
        out[OUT_VALID + (size_t)k * (NCELL + 1) + s] = val ? 1.0f : 0.0f;
    }
}

extern "C" void kernel_launch(void* const* d_in, const int* in_sizes, int n_in,
                              void* d_out, int out_size, void* d_ws, size_t ws_size,
                              hipStream_t stream) {
    const float* x = (const float*)d_in[0];   // (1,1024,1024,3) f32
    const float* W = (const float*)d_in[1];   // (12288,10) f32
    const float* b = (const float*)d_in[2];   // (10,) f32
    float* out     = (float*)d_out;
    float* partial = (float*)d_ws;            // 64*61*61*10 f32 = 9.5 MB

    k1a_partial<<<dim3(1984), dim3(256), 0, stream>>>(x, W, partial);
    k1b_softmax<<<dim3(61),   dim3(640), 0, stream>>>(partial, b, out);
    k2_cc_boxes<<<dim3(KCLS), dim3(1024), 0, stream>>>(out);
}

// Round 6
// 145.187 us; speedup vs baseline: 1.1112x; 1.1112x over previous
//
#include <hip/hip_runtime.h>
#include <cmath>

#define KCLS 10
#define NCELL 3721          // 61*61
#define BIGV  0x0FFFFFFF

// d_out layout (all float32), concatenated in reference return order
#define OUT_PROB 0
#define OUT_LAB  37210
#define OUT_BOX  74420
#define OUT_VALID 223300

// padded pixel-row: raw float index p stored at p + 4*(p/48).
// Lane c reads b128 @ dword 13*(c+tq)*4... (52-byte row stride): banks walk
// all 8 quads with period 8 -> minimal-conflict ds_read_b128 (verified r3-r5).
#define XROW_PAD 3328       // 3072 + 4*64

// helper: element n (compile-time after unroll) of a float4[10] block
#define WF(q, n) ( ((n)&3)==0 ? (q)[(n)>>2].x : ((n)&3)==1 ? (q)[(n)>>2].y : \
                   ((n)&3)==2 ? (q)[(n)>>2].z : (q)[(n)>>2].w )

// ---------------- Stage 1a: partial logits ---------------------------------
// Grid 1984 = 64 i-rows x 31 r-pairs; 256 threads = 4 waves (t-quarters),
// lane = patch column c. Pipe-split operand delivery:
//   x: per-lane ds_read_b128 from LDS-staged padded pixel rows (lgkmcnt)
//   W: wave-uniform 16B global loads -> 1 L1 line each / scalar path (vmcnt)
//   80 v_fma per u-step (2 patch rows x 10 classes x 4 d)
// No W in LDS -> 31.5 KB LDS -> 5 blocks/CU = 20 waves/CU latency hiding.
__global__ __launch_bounds__(256, 4) void k1a_partial(
    const float* __restrict__ x, const float* __restrict__ W,
    float* __restrict__ partial)
{
    const int tid  = threadIdx.x;
    const int bid  = blockIdx.x;          // 0..1983
    const int ip   = bid / 31;            // 0..63  pixel-row-in-patch
    const int g    = bid - ip * 31;       // 0..30  r-pair
    const int ra   = g * 2;               // even patch row
    const int lane = tid & 63;
    const int tq   = tid >> 6;            // t-quarter 0..3
    const int cc   = (lane < 61) ? lane : 60;   // dup lanes, add/write-guarded

    __shared__ float xrowA[XROW_PAD];     // 13.3 KiB
    __shared__ float xrowB[XROW_PAD];     // 13.3 KiB
    __shared__ float red[2][61][KCLS];    // 4.9 KiB

    // zero red (covered by the staging barrier)
    for (int s = tid; s < 2 * 61 * KCLS; s += 256) ((float*)red)[s] = 0.0f;

    // stage 2 pixel rows (patch rows ra, ra+1), padded
    {
        const int prA = (ra * 16) + ip;                  // <= 60*16+63 = 1023
        int prB = (ra + 1) * 16 + ip;
        if (prB > 1023) prB = 1023;                      // g=30 dup, write-guarded
        const float* gA = x + (size_t)prA * 3072;
        const float* gB = x + (size_t)prB * 3072;
#pragma unroll
        for (int j = 0; j < 3; ++j) {
            const int idx = tid + (j << 8);              // 0..767 float4s
            const int p   = idx << 2;                    // p%48<=44: same pad group
            const int dst = p + ((p / 48) << 2);
            const float4 va = *(const float4*)(gA + p);
            xrowA[dst] = va.x; xrowA[dst+1] = va.y; xrowA[dst+2] = va.z; xrowA[dst+3] = va.w;
            const float4 vb = *(const float4*)(gB + p);
            xrowB[dst] = vb.x; xrowB[dst+1] = vb.y; xrowB[dst+2] = vb.z; xrowB[dst+3] = vb.w;
        }
    }
    __syncthreads();

    float accA[KCLS], accB[KCLS];
#pragma unroll
    for (int k = 0; k < KCLS; ++k) { accA[k] = 0.0f; accB[k] = 0.0f; }

    // this wave's 48-d window of W (wave-uniform base)
    const float* wb = W + (size_t)(ip * 192 + tq * 48) * KCLS;
    const float* lA = &xrowA[52 * (cc + tq)];
    const float* lB = &xrowB[52 * (cc + tq)];

#pragma unroll 2
    for (int u = 0; u < 12; ++u) {
        const float4 xa = *(const float4*)(lA + (u << 2));
        const float4 xb = *(const float4*)(lB + (u << 2));
        const float* wu = wb + 40 * u;        // uniform; 10x 16B = 160B contig
        float4 wq[10];
#pragma unroll
        for (int q = 0; q < 10; ++q) wq[q] = *(const float4*)(wu + (q << 2));
#pragma unroll
        for (int k = 0; k < KCLS; ++k) {
            accA[k] += xa.x * WF(wq, k);       accB[k] += xb.x * WF(wq, k);
            accA[k] += xa.y * WF(wq, 10 + k);  accB[k] += xb.y * WF(wq, 10 + k);
            accA[k] += xa.z * WF(wq, 20 + k);  accB[k] += xb.z * WF(wq, 20 + k);
            accA[k] += xa.w * WF(wq, 30 + k);  accB[k] += xb.w * WF(wq, 30 + k);
        }
    }

    // cross-wave reduce (ds_add_f32); order nondeterminism ~1e-7 vs 1e-3 margins
    if (lane < 61) {
#pragma unroll
        for (int k = 0; k < KCLS; ++k) {
            atomicAdd(&red[0][cc][k], accA[k]);
            atomicAdd(&red[1][cc][k], accB[k]);
        }
    }
    __syncthreads();

    // write partials: slot ip, rows ra and ra+1 (layout [ip][r][c][k])
    for (int t = tid; t < 610; t += 256)
        partial[(size_t)ip * 37210 + (size_t)ra * 610 + t] = ((const float*)red)[t];
    if (ra + 1 <= 60) {
        for (int t = tid; t < 610; t += 256)
            partial[(size_t)ip * 37210 + (size_t)(ra + 1) * 610 + t]
                = ((const float*)red)[610 + t];
    }
}

// ---------------- Stage 1b: reduce partials + bias + softmax ---------------
__global__ __launch_bounds__(640) void k1b_softmax(
    const float* __restrict__ partial, const float* __restrict__ b,
    float* __restrict__ out)
{
    const int r   = blockIdx.x;           // 0..60
    const int tid = threadIdx.x;
    __shared__ double lgs[61][KCLS];

    if (tid < 610) {
        const int c = tid / 10, k = tid - c * 10;
        double s = (double)b[k];
        const float* p = partial + (size_t)r * 610 + tid;
#pragma unroll 8
        for (int ip = 0; ip < 64; ++ip)
            s += (double)p[(size_t)ip * 37210];
        lgs[c][k] = s;
    }
    __syncthreads();

    if (tid < 61) {
        double l[KCLS];
#pragma unroll
        for (int k = 0; k < KCLS; ++k) l[k] = lgs[tid][k];
        double m = l[0];
#pragma unroll
        for (int k = 1; k < KCLS; ++k) m = fmax(m, l[k]);
        double e[KCLS], ssum = 0.0;
#pragma unroll
        for (int k = 0; k < KCLS; ++k) { e[k] = exp(l[k] - m); ssum += e[k]; }
        const double inv = 1.0 / ssum;
        float* po = out + OUT_PROB + (size_t)(r * 61 + tid) * KCLS;
#pragma unroll
        for (int k = 0; k < KCLS; ++k) po[k] = (float)(e[k] * inv);
    }
}

// ---------------- Stage 2+3 fused: CC (union-find hooking) + boxes ---------
// One block per class. Labels stored as LDS OFFSETS (off = (r+1)*64 + c+1):
// min-off == min-idx (both lexicographic in (r,c)). Root chase + atomicMin
// hooking = path compression -> ~3-6 rounds instead of O(diameter).
__global__ __launch_bounds__(1024) void k2_cc_boxes(float* __restrict__ out)
{
    const int k   = blockIdx.x;
    const int tid = threadIdx.x;

    __shared__ int lab[63 * 64];
    __shared__ int act[NCELL];
    __shared__ int nact, changed;
    __shared__ int rmn[NCELL + 1], rmx[NCELL + 1], cmn[NCELL + 1], cmx[NCELL + 1];

    for (int idx = tid; idx < 63 * 64; idx += 1024) lab[idx] = BIGV;
    for (int s = tid; s <= NCELL; s += 1024) {
        rmn[s] = 0x7fffffff; cmn[s] = 0x7fffffff; rmx[s] = -1; cmx[s] = -1;
    }
    if (tid == 0) nact = 0;
    __syncthreads();

    for (int idx = tid; idx < NCELL; idx += 1024) {
        const float pv = out[OUT_PROB + (size_t)idx * KCLS + k];
        if (pv > 0.7f) {
            const int r = idx / 61, c = idx - r * 61;
            const int off = (r + 1) * 64 + (c + 1);
            lab[off] = off;
            act[atomicAdd(&nact, 1)] = off;
        }
    }
    __syncthreads();
    const int na = nact;

    for (int round = 0; round < 128; ++round) {
        if (tid == 0) changed = 0;
        __syncthreads();
        bool ch = false;
        for (int ii = tid; ii < na; ii += 1024) {
            const int off = act[ii];
            const int v = lab[off];
            int m = v, t;
            t = lab[off - 1];  if (t < m) m = t;
            t = lab[off + 1];  if (t < m) m = t;
            t = lab[off - 64]; if (t < m) m = t;
            t = lab[off + 64]; if (t < m) m = t;
            if (m < v) {
                int p = lab[m];                       // chase to current root
                while (p < m) { m = p; p = lab[m]; }  // strictly decreasing
                atomicMin(&lab[off], m);              // compress self
                atomicMin(&lab[v],   m);              // hook old root (union)
                ch = true;
            }
        }
        if (ch) changed = 1;       // benign race
        __syncthreads();
        if (changed == 0) break;   // no writes between the barriers -> uniform
        __syncthreads();           // protect next round's reset
    }

    // write labels (convert off -> idx+1)
    for (int idx = tid; idx < NCELL; idx += 1024) {
        const int r = idx / 61, c = idx - r * 61;
        const int v = lab[(r + 1) * 64 + (c + 1)];
        const int lv = (v < BIGV) ? ((v >> 6) * 61 - 61 + (v & 63)) : 0;
        out[OUT_LAB + (size_t)idx * KCLS + k] = (float)lv;
    }

    // boxes: segment min/max over active cells only
    for (int ii = tid; ii < na; ii += 1024) {
        const int off = act[ii];
        const int v = lab[off];
        const int lb = (v >> 6) * 61 - 61 + (v & 63);
        const int r = (off >> 6) - 1, c = (off & 63) - 1;
        atomicMin(&rmn[lb], r); atomicMax(&rmx[lb], r);
        atomicMin(&cmn[lb], c); atomicMax(&cmx[lb], c);
    }
    __syncthreads();

    for (int s = tid; s <= NCELL; s += 1024) {
        const bool val = (s > 0) && (rmx[s] >= 0);
        float* bo = out + OUT_BOX + (size_t)(k * (NCELL + 1) + s) * 4;
        if (val) {
            bo[0] = (float)(rmn[s] - 1);
            bo[1] = (float)(cmn[s] - 1);
            bo[2] = (float)(rmx[s] + 1);
            bo[3] = (float)(cmx[s] + 1);
        } else {
            bo[0] = 0.0f; bo[1] = 0.0f; bo[2] = 0.0f; bo[3] = 0.0f;
        }
        out[OUT_VALID + (size_t)k * (NCELL + 1) + s] = val ? 1.0f : 0.0f;
    }
}

extern "C" void kernel_launch(void* const* d_in, const int* in_sizes, int n_in,
                              void* d_out, int out_size, void* d_ws, size_t ws_size,
                              hipStream_t stream) {
    const float* x = (const float*)d_in[0];   // (1,1024,1024,3) f32
    const float* W = (const float*)d_in[1];   // (12288,10) f32
    const float* b = (const float*)d_in[2];   // (10,) f32
    float* out     = (float*)d_out;
    float* partial = (float*)d_ws;            // 64*61*61*10 f32 = 9.5 MB

    k1a_partial<<<dim3(1984), dim3(256), 0, stream>>>(x, W, partial);
    k1b_softmax<<<dim3(61),   dim3(640), 0, stream>>>(partial, b, out);
    k2_cc_boxes<<<dim3(KCLS), dim3(1024), 0, stream>>>(out);
}

// Round 7
// 142.168 us; speedup vs baseline: 1.1348x; 1.0212x over previous
//
#include <hip/hip_runtime.h>
#include <cmath>

#define KCLS 10
#define NCELL 3721          // 61*61
#define BIGV  0x0FFFFFFF

// d_out layout (all float32), concatenated in reference return order
#define OUT_PROB 0
#define OUT_LAB  37210
#define OUT_BOX  74420
#define OUT_VALID 223300

// helper: element n (compile-time after unroll) of a float4[10] block
#define WF(q, n) ( ((n)&3)==0 ? (q)[(n)>>2].x : ((n)&3)==1 ? (q)[(n)>>2].y : \
                   ((n)&3)==2 ? (q)[(n)>>2].z : (q)[(n)>>2].w )

// ---------------- Stage 1a: partial logits ---------------------------------
// Grid 1984 = 64 i-rows x 31 r-pairs; 256 threads = 4 waves (t-quarters),
// lane = patch column c. NO LDS staging, NO barrier in the main loop:
//   x: per-lane global_load_dwordx4, base + immediate offset (u*16B); the
//      2-row 24KB working set is L1/L2-cached and fully consumed.
//   W: wave-uniform 16B global loads (one L1 line each).
// Loads are spread through all 12 u-steps of all free-running waves ->
// continuous HBM demand (fix for the staged-phase starvation seen r2-r6).
// LDS = 4.9KB only -> ~6 blocks/CU (24 waves) at launch_bounds(256,6).
__global__ __launch_bounds__(256, 6) void k1a_partial(
    const float* __restrict__ x, const float* __restrict__ W,
    float* __restrict__ partial)
{
    const int tid  = threadIdx.x;
    const int bid  = blockIdx.x;          // 0..1983
    const int ip   = bid / 31;            // 0..63  pixel-row-in-patch
    const int g    = bid - ip * 31;       // 0..30  r-pair
    const int ra   = g * 2;               // even patch row
    const int lane = tid & 63;
    const int tq   = tid >> 6;            // t-quarter 0..3
    const int cc   = (lane < 61) ? lane : 60;   // dup lanes, add/write-guarded

    __shared__ float red[2][61][KCLS];    // 4.9 KiB

    for (int s = tid; s < 2 * 61 * KCLS; s += 256) ((float*)red)[s] = 0.0f;
    __syncthreads();

    // row pointers: lane c, quarter tq -> floats 48*(c+tq) .. +47 of each row
    const int prA = ra * 16 + ip;                    // <= 60*16+63 = 1023
    int prB = (ra + 1) * 16 + ip;
    if (prB > 1023) prB = 1023;                      // g=30 dup, write-guarded
    const float* lA = x + (size_t)prA * 3072 + 48 * (cc + tq);
    const float* lB = x + (size_t)prB * 3072 + 48 * (cc + tq);
    const float* wb = W + (size_t)(ip * 192 + tq * 48) * KCLS;  // uniform

    float accA[KCLS], accB[KCLS];
#pragma unroll
    for (int k = 0; k < KCLS; ++k) { accA[k] = 0.0f; accB[k] = 0.0f; }

#pragma unroll 2
    for (int u = 0; u < 12; ++u) {
        const float4 xa = *(const float4*)(lA + (u << 2));   // imm offset u*16B
        const float4 xb = *(const float4*)(lB + (u << 2));
        const float* wu = wb + 40 * u;        // uniform; 10x 16B contiguous
        float4 wq[10];
#pragma unroll
        for (int q = 0; q < 10; ++q) wq[q] = *(const float4*)(wu + (q << 2));
#pragma unroll
        for (int k = 0; k < KCLS; ++k) {
            accA[k] += xa.x * WF(wq, k);       accB[k] += xb.x * WF(wq, k);
            accA[k] += xa.y * WF(wq, 10 + k);  accB[k] += xb.y * WF(wq, 10 + k);
            accA[k] += xa.z * WF(wq, 20 + k);  accB[k] += xb.z * WF(wq, 20 + k);
            accA[k] += xa.w * WF(wq, 30 + k);  accB[k] += xb.w * WF(wq, 30 + k);
        }
    }

    // cross-wave reduce (ds_add_f32); order nondeterminism ~1e-7 vs 1e-3 margins
    if (lane < 61) {
#pragma unroll
        for (int k = 0; k < KCLS; ++k) {
            atomicAdd(&red[0][cc][k], accA[k]);
            atomicAdd(&red[1][cc][k], accB[k]);
        }
    }
    __syncthreads();

    // write partials: slot ip, rows ra and ra+1 (layout [ip][r][c][k])
    for (int t = tid; t < 610; t += 256)
        partial[(size_t)ip * 37210 + (size_t)ra * 610 + t] = ((const float*)red)[t];
    if (ra + 1 <= 60) {
        for (int t = tid; t < 610; t += 256)
            partial[(size_t)ip * 37210 + (size_t)(ra + 1) * 610 + t]
                = ((const float*)red)[610 + t];
    }
}

// ---------------- Stage 1b: reduce partials + bias + softmax ---------------
__global__ __launch_bounds__(640) void k1b_softmax(
    const float* __restrict__ partial, const float* __restrict__ b,
    float* __restrict__ out)
{
    const int r   = blockIdx.x;           // 0..60
    const int tid = threadIdx.x;
    __shared__ double lgs[61][KCLS];

    if (tid < 610) {
        const int c = tid / 10, k = tid - c * 10;
        double s = (double)b[k];
        const float* p = partial + (size_t)r * 610 + tid;
#pragma unroll 8
        for (int ip = 0; ip < 64; ++ip)
            s += (double)p[(size_t)ip * 37210];
        lgs[c][k] = s;
    }
    __syncthreads();

    if (tid < 61) {
        double l[KCLS];
#pragma unroll
        for (int k = 0; k < KCLS; ++k) l[k] = lgs[tid][k];
        double m = l[0];
#pragma unroll
        for (int k = 1; k < KCLS; ++k) m = fmax(m, l[k]);
        double e[KCLS], ssum = 0.0;
#pragma unroll
        for (int k = 0; k < KCLS; ++k) { e[k] = exp(l[k] - m); ssum += e[k]; }
        const double inv = 1.0 / ssum;
        float* po = out + OUT_PROB + (size_t)(r * 61 + tid) * KCLS;
#pragma unroll
        for (int k = 0; k < KCLS; ++k) po[k] = (float)(e[k] * inv);
    }
}

// ---------------- Stage 2+3 fused: CC (union-find hooking) + boxes ---------
// One block per class. Labels stored as LDS OFFSETS (off = (r+1)*64 + c+1):
// min-off == min-idx (both lexicographic in (r,c)). Root chase + atomicMin
// hooking = path compression -> ~3-6 rounds instead of O(diameter).
__global__ __launch_bounds__(1024) void k2_cc_boxes(float* __restrict__ out)
{
    const int k   = blockIdx.x;
    const int tid = threadIdx.x;

    __shared__ int lab[63 * 64];
    __shared__ int act[NCELL];
    __shared__ int nact, changed;
    __shared__ int rmn[NCELL + 1], rmx[NCELL + 1], cmn[NCELL + 1], cmx[NCELL + 1];

    for (int idx = tid; idx < 63 * 64; idx += 1024) lab[idx] = BIGV;
    for (int s = tid; s <= NCELL; s += 1024) {
        rmn[s] = 0x7fffffff; cmn[s] = 0x7fffffff; rmx[s] = -1; cmx[s] = -1;
    }
    if (tid == 0) nact = 0;
    __syncthreads();

    for (int idx = tid; idx < NCELL; idx += 1024) {
        const float pv = out[OUT_PROB + (size_t)idx * KCLS + k];
        if (pv > 0.7f) {
            const int r = idx / 61, c = idx - r * 61;
            const int off = (r + 1) * 64 + (c + 1);
            lab[off] = off;
            act[atomicAdd(&nact, 1)] = off;
        }
    }
    __syncthreads();
    const int na = nact;

    for (int round = 0; round < 128; ++round) {
        if (tid == 0) changed = 0;
        __syncthreads();
        bool ch = false;
        for (int ii = tid; ii < na; ii += 1024) {
            const int off = act[ii];
            const int v = lab[off];
            int m = v, t;
            t = lab[off - 1];  if (t < m) m = t;
            t = lab[off + 1];  if (t < m) m = t;
            t = lab[off - 64]; if (t < m) m = t;
            t = lab[off + 64]; if (t < m) m = t;
            if (m < v) {
                int p = lab[m];                       // chase to current root
                while (p < m) { m = p; p = lab[m]; }  // strictly decreasing
                atomicMin(&lab[off], m);              // compress self
                atomicMin(&lab[v],   m);              // hook old root (union)
                ch = true;
            }
        }
        if (ch) changed = 1;       // benign race
        __syncthreads();
        if (changed == 0) break;   // no writes between the barriers -> uniform
        __syncthreads();           // protect next round's reset
    }

    // write labels (convert off -> idx+1)
    for (int idx = tid; idx < NCELL; idx += 1024) {
        const int r = idx / 61, c = idx - r * 61;
        const int v = lab[(r + 1) * 64 + (c + 1)];
        const int lv = (v < BIGV) ? ((v >> 6) * 61 - 61 + (v & 63)) : 0;
        out[OUT_LAB + (size_t)idx * KCLS + k] = (float)lv;
    }

    // boxes: segment min/max over active cells only
    for (int ii = tid; ii < na; ii += 1024) {
        const int off = act[ii];
        const int v = lab[off];
        const int lb = (v >> 6) * 61 - 61 + (v & 63);
        const int r = (off >> 6) - 1, c = (off & 63) - 1;
        atomicMin(&rmn[lb], r); atomicMax(&rmx[lb], r);
        atomicMin(&cmn[lb], c); atomicMax(&cmx[lb], c);
    }
    __syncthreads();

    for (int s = tid; s <= NCELL; s += 1024) {
        const bool val = (s > 0) && (rmx[s] >= 0);
        float* bo = out + OUT_BOX + (size_t)(k * (NCELL + 1) + s) * 4;
        if (val) {
            bo[0] = (float)(rmn[s] - 1);
            bo[1] = (float)(cmn[s] - 1);
            bo[2] = (float)(rmx[s] + 1);
            bo[3] = (float)(cmx[s] + 1);
        } else {
            bo[0] = 0.0f; bo[1] = 0.0f; bo[2] = 0.0f; bo[3] = 0.0f;
        }
        out[OUT_VALID + (size_t)k * (NCELL + 1) + s] = val ? 1.0f : 0.0f;
    }
}

extern "C" void kernel_launch(void* const* d_in, const int* in_sizes, int n_in,
                              void* d_out, int out_size, void* d_ws, size_t ws_size,
                              hipStream_t stream) {
    const float* x = (const float*)d_in[0];   // (1,1024,1024,3) f32
    const float* W = (const float*)d_in[1];   // (12288,10) f32
    const float* b = (const float*)d_in[2];   // (10,) f32
    float* out     = (float*)d_out;
    float* partial = (float*)d_ws;            // 64*61*61*10 f32 = 9.5 MB

    k1a_partial<<<dim3(1984), dim3(256), 0, stream>>>(x, W, partial);
    k1b_softmax<<<dim3(61),   dim3(640), 0, stream>>>(partial, b, out);
    k2_cc_boxes<<<dim3(KCLS), dim3(1024), 0, stream>>>(out);
}

// Round 8
// 114.717 us; speedup vs baseline: 1.4063x; 1.2393x over previous
//
#include <hip/hip_runtime.h>
#include <cmath>

#define KCLS 10
#define NCELL 3721          // 61*61
#define BIGV  0x0FFFFFFF

// d_out layout (all float32), concatenated in reference return order
#define OUT_PROB 0
#define OUT_LAB  37210
#define OUT_BOX  74420
#define OUT_VALID 223300

// ---------------------------------------------------------------------------
// DPP wave64 sum on the VALU pipe (v_add_f32_dpp); result lands in lane 63.
#define DPPADD(x, ctrl) \
    x += __int_as_float(__builtin_amdgcn_update_dpp( \
        0, __float_as_int(x), ctrl, 0xf, 0xf, true))

__device__ __forceinline__ float wave_sum64(float x) {
    DPPADD(x, 0x111);   // row_shr:1
    DPPADD(x, 0x112);   // row_shr:2
    DPPADD(x, 0x114);   // row_shr:4
    DPPADD(x, 0x118);   // row_shr:8
    DPPADD(x, 0x142);   // row_bcast:15
    DPPADD(x, 0x143);   // row_bcast:31
    return x;           // lane 63 holds the 64-lane sum
}

// ---------------- Stage 0: transpose W -> WT[k][d] -------------------------
// Makes the weight operand lane-coalesced for k1a (lane = d). 480 KB once.
__global__ __launch_bounds__(256) void k0_transpose(
    const float* __restrict__ W, float* __restrict__ WT)
{
    const int d = blockIdx.x * 256 + threadIdx.x;   // 48 blocks -> 0..12287
    const float2 a0 = *(const float2*)(W + (size_t)d * KCLS + 0);
    const float2 a1 = *(const float2*)(W + (size_t)d * KCLS + 2);
    const float2 a2 = *(const float2*)(W + (size_t)d * KCLS + 4);
    const float2 a3 = *(const float2*)(W + (size_t)d * KCLS + 6);
    const float2 a4 = *(const float2*)(W + (size_t)d * KCLS + 8);
    WT[0 * 12288 + d] = a0.x;  WT[1 * 12288 + d] = a0.y;
    WT[2 * 12288 + d] = a1.x;  WT[3 * 12288 + d] = a1.y;
    WT[4 * 12288 + d] = a2.x;  WT[5 * 12288 + d] = a2.y;
    WT[6 * 12288 + d] = a3.x;  WT[7 * 12288 + d] = a3.y;
    WT[8 * 12288 + d] = a4.x;  WT[9 * 12288 + d] = a4.y;
}

// ---------------- Stage 1: logits + softmax (one kernel, no partials) ------
// 488 blocks = 61 rows x 8 col-groups; 512 threads = 8 waves; lane = d.
// Thread tid owns d-pairs d0 = 2*tid + 1024*u, u=0..11 (block covers all K).
// Both operand streams lane-coalesced (512B/wave/instr):
//   wt[k] = WT[k*12288 + d0]   (10 float2 loads)
//   xv[p] = x[(16r+i)*3072 + 48*(c0+p) + t]  (8 float2, d-chunk never
//           straddles pixel rows: 2 | 192)
// 8x10 register outer product: 160 FMA / 18 loads per iter; acc[8][10]=80
// VGPR, two-phase xv[4] keeps total ~120 -> 4 waves/SIMD, no spill.
__global__ __launch_bounds__(512, 4) void k1a_logits(
    const float* __restrict__ x, const float* __restrict__ WT,
    const float* __restrict__ b, float* __restrict__ out)
{
    const int tid = threadIdx.x;
    const int r   = blockIdx.x >> 3;             // 0..60
    const int cg  = blockIdx.x & 7;
    const int c0  = (cg == 7) ? 53 : cg * 8;     // cols c0..c0+7 all <= 60
                                                  // (overlap cols recompute
                                                  //  bit-identically)
    __shared__ float red[8][8][KCLS];            // [wave][patch][k] 2.5 KiB

    float acc[8][KCLS];
#pragma unroll
    for (int p = 0; p < 8; ++p)
#pragma unroll
        for (int k = 0; k < KCLS; ++k) acc[p][k] = 0.0f;

    // d0 = i*192 + t
    int i = (2 * tid) / 192;
    int t = (2 * tid) - i * 192;
    const float* wtb = WT + 2 * tid;             // + k*12288 + 1024*u

    for (int u = 0; u < 12; ++u) {
        const float* xb = x + (size_t)(r * 16 + i) * 3072 + 48 * c0 + t;
        const float* wb = wtb + (u << 10);

        float2 wt[KCLS];
#pragma unroll
        for (int k = 0; k < KCLS; ++k) wt[k] = *(const float2*)(wb + 12288 * k);

        float2 xv[4];
#pragma unroll
        for (int p = 0; p < 4; ++p) xv[p] = *(const float2*)(xb + 48 * p);
#pragma unroll
        for (int p = 0; p < 4; ++p)
#pragma unroll
            for (int k = 0; k < KCLS; ++k)
                acc[p][k] += xv[p].x * wt[k].x + xv[p].y * wt[k].y;

#pragma unroll
        for (int p = 0; p < 4; ++p) xv[p] = *(const float2*)(xb + 192 + 48 * p);
#pragma unroll
        for (int p = 0; p < 4; ++p)
#pragma unroll
            for (int k = 0; k < KCLS; ++k)
                acc[4 + p][k] += xv[p].x * wt[k].x + xv[p].y * wt[k].y;

        // d0 += 1024 = 5*192 + 64
        t += 64; i += 5;
        if (t >= 192) { t -= 192; ++i; }
    }

    // wave reduction (VALU pipe), partials to LDS
    const int w = tid >> 6;
#pragma unroll
    for (int p = 0; p < 8; ++p)
#pragma unroll
        for (int k = 0; k < KCLS; ++k) {
            const float s = wave_sum64(acc[p][k]);
            if ((tid & 63) == 63) red[w][p][k] = s;
        }
    __syncthreads();

    // 8 threads: f64 cross-wave sum + bias + softmax (r1-verified numerics)
    if (tid < 8) {
        const int cc = c0 + tid;
        double l[KCLS];
#pragma unroll
        for (int k = 0; k < KCLS; ++k) {
            double s = (double)b[k];
#pragma unroll
            for (int w2 = 0; w2 < 8; ++w2) s += (double)red[w2][tid][k];
            l[k] = s;
        }
        double m = l[0];
#pragma unroll
        for (int k = 1; k < KCLS; ++k) m = fmax(m, l[k]);
        double e[KCLS], ssum = 0.0;
#pragma unroll
        for (int k = 0; k < KCLS; ++k) { e[k] = exp(l[k] - m); ssum += e[k]; }
        const double inv = 1.0 / ssum;
        float* po = out + OUT_PROB + (size_t)(r * 61 + cc) * KCLS;
#pragma unroll
        for (int k = 0; k < KCLS; ++k) po[k] = (float)(e[k] * inv);
    }
}

// ---------------- Stage 2+3 fused: CC (union-find hooking) + boxes ---------
// One block per class. Labels stored as LDS OFFSETS (off = (r+1)*64 + c+1):
// min-off == min-idx (both lexicographic in (r,c)). Root chase + atomicMin
// hooking = path compression -> ~3-6 rounds instead of O(diameter).
__global__ __launch_bounds__(1024) void k2_cc_boxes(float* __restrict__ out)
{
    const int k   = blockIdx.x;
    const int tid = threadIdx.x;

    __shared__ int lab[63 * 64];
    __shared__ int act[NCELL];
    __shared__ int nact, changed;
    __shared__ int rmn[NCELL + 1], rmx[NCELL + 1], cmn[NCELL + 1], cmx[NCELL + 1];

    for (int idx = tid; idx < 63 * 64; idx += 1024) lab[idx] = BIGV;
    for (int s = tid; s <= NCELL; s += 1024) {
        rmn[s] = 0x7fffffff; cmn[s] = 0x7fffffff; rmx[s] = -1; cmx[s] = -1;
    }
    if (tid == 0) nact = 0;
    __syncthreads();

    for (int idx = tid; idx < NCELL; idx += 1024) {
        const float pv = out[OUT_PROB + (size_t)idx * KCLS + k];
        if (pv > 0.7f) {
            const int r = idx / 61, c = idx - r * 61;
            const int off = (r + 1) * 64 + (c + 1);
            lab[off] = off;
            act[atomicAdd(&nact, 1)] = off;
        }
    }
    __syncthreads();
    const int na = nact;

    for (int round = 0; round < 128; ++round) {
        if (tid == 0) changed = 0;
        __syncthreads();
        bool ch = false;
        for (int ii = tid; ii < na; ii += 1024) {
            const int off = act[ii];
            const int v = lab[off];
            int m = v, t;
            t = lab[off - 1];  if (t < m) m = t;
            t = lab[off + 1];  if (t < m) m = t;
            t = lab[off - 64]; if (t < m) m = t;
            t = lab[off + 64]; if (t < m) m = t;
            if (m < v) {
                int p = lab[m];                       // chase to current root
                while (p < m) { m = p; p = lab[m]; }  // strictly decreasing
                atomicMin(&lab[off], m);              // compress self
                atomicMin(&lab[v],   m);              // hook old root (union)
                ch = true;
            }
        }
        if (ch) changed = 1;       // benign race
        __syncthreads();
        if (changed == 0) break;   // no writes between the barriers -> uniform
        __syncthreads();           // protect next round's reset
    }

    // write labels (convert off -> idx+1)
    for (int idx = tid; idx < NCELL; idx += 1024) {
        const int r = idx / 61, c = idx - r * 61;
        const int v = lab[(r + 1) * 64 + (c + 1)];
        const int lv = (v < BIGV) ? ((v >> 6) * 61 - 61 + (v & 63)) : 0;
        out[OUT_LAB + (size_t)idx * KCLS + k] = (float)lv;
    }

    // boxes: segment min/max over active cells only
    for (int ii = tid; ii < na; ii += 1024) {
        const int off = act[ii];
        const int v = lab[off];
        const int lb = (v >> 6) * 61 - 61 + (v & 63);
        const int r = (off >> 6) - 1, c = (off & 63) - 1;
        atomicMin(&rmn[lb], r); atomicMax(&rmx[lb], r);
        atomicMin(&cmn[lb], c); atomicMax(&cmx[lb], c);
    }
    __syncthreads();

    for (int s = tid; s <= NCELL; s += 1024) {
        const bool val = (s > 0) && (rmx[s] >= 0);
        float* bo = out + OUT_BOX + (size_t)(k * (NCELL + 1) + s) * 4;
        if (val) {
            bo[0] = (float)(rmn[s] - 1);
            bo[1] = (float)(cmn[s] - 1);
            bo[2] = (float)(rmx[s] + 1);
            bo[3] = (float)(cmx[s] + 1);
        } else {
            bo[0] = 0.0f; bo[1] = 0.0f; bo[2] = 0.0f; bo[3] = 0.0f;
        }
        out[OUT_VALID + (size_t)k * (NCELL + 1) + s] = val ? 1.0f : 0.0f;
    }
}

extern "C" void kernel_launch(void* const* d_in, const int* in_sizes, int n_in,
                              void* d_out, int out_size, void* d_ws, size_t ws_size,
                              hipStream_t stream) {
    const float* x = (const float*)d_in[0];   // (1,1024,1024,3) f32
    const float* W = (const float*)d_in[1];   // (12288,10) f32
    const float* b = (const float*)d_in[2];   // (10,) f32
    float* out = (float*)d_out;
    float* WT  = (float*)d_ws;                // 10*12288 f32 = 480 KB

    k0_transpose<<<dim3(48),  dim3(256),  0, stream>>>(W, WT);
    k1a_logits  <<<dim3(488), dim3(512),  0, stream>>>(x, WT, b, out);
    k2_cc_boxes <<<dim3(KCLS), dim3(1024), 0, stream>>>(out);
}